// Round 5
// baseline (2361.397 us; speedup 1.0000x reference)
//
#include <hip/hip_runtime.h>
#include <hip/hip_bf16.h>
#include <stdint.h>

typedef __bf16 bf16x8 __attribute__((ext_vector_type(8)));
typedef float f32x4 __attribute__((ext_vector_type(4)));

// ---- helpers ------------------------------------------------------------

__device__ inline void gload_lds16(const void* g, void* lds) {
  __builtin_amdgcn_global_load_lds(
      (const __attribute__((address_space(1))) uint32_t*)(uintptr_t)g,
      (__attribute__((address_space(3))) uint32_t*)(uintptr_t)lds,
      16, 0, 0);
}

__device__ inline short f2bf(float f) {
  union { float f; uint32_t u; } x; x.f = f;
  uint32_t u = x.u;
  u += 0x7fffu + ((u >> 16) & 1u);   // RNE
  return (short)(u >> 16);
}

#define BAR() do { asm volatile("" ::: "memory"); \
                   __builtin_amdgcn_s_barrier();  \
                   asm volatile("" ::: "memory"); } while (0)

// ---- fp32 -> bf16 convert (vectorized) ----------------------------------

__global__ __launch_bounds__(256) void cvt_f32_bf16(
    const float* __restrict__ in, short* __restrict__ out, int n4) {
  int i = blockIdx.x * 256 + threadIdx.x;
  if (i < n4) {
    float4 v = reinterpret_cast<const float4*>(in)[i];
    short4 o;
    o.x = f2bf(v.x); o.y = f2bf(v.y); o.z = f2bf(v.z); o.w = f2bf(v.w);
    reinterpret_cast<short4*>(out)[i] = o;
  }
}

// ---- GEMM: C[M,N] = A[M,K] @ B[N,K]^T, bf16 in, fp32 acc ---------------
// Cross-tile fragment read-ahead, gray-code quadrants, 2 barriers/tile.
// 256x256 tile, BK=64, 8 waves (2Mx4N), per-wave 128x64 = acc[8][4].
//
// LDS: 2 buffers x 4 slots x [128 rows x 64 k] bf16 = 128 KiB.
//   slot0 A0 (m-frags 0-3), slot1 A1 (m-frags 4-7),
//   slot2 B0 (n-frags 0-1), slot3 B1 (n-frags 2-3).
//
// Per tile t (cur=t&1, nxt=cur^1); a0q,b0q already in regs on entry
// (read during t-1's M4, after t-1's mid-barrier published them):
//   M1: R(b1q<-B1[cur]) | S1: stage A0,B0(t+1)->nxt | MFMA Q(m0-3,n0-1)
//   M2: R(a1q<-A1[cur]) | S2: stage A1,B1(t+1)->nxt | MFMA Q(m0-3,n2-3)
//   M3: MFMA Q(m4-7,n2-3) ; then vmcnt(4) [S1 done] + BAR  (mid publish)
//   M4: R(a0q',b0q'<-A0,B0[nxt]) | MFMA Q(m4-7,n0-1)
//   end: vmcnt(0) [S2 done] + BAR
// Every cluster's operands were read >=1 cluster earlier -> no head-of-
// tile read burst; reads overlap MFMA via counted lgkmcnt (compiler).
// Race ledger: S1/S2 writes to buf[nxt] are >=1 barrier after buf[nxt]'s
// last reads (tile t-1's M1/M2-region reads, separated by end-BAR(t-1));
// M4's reads of buf[nxt] follow the mid-barrier that drained S1.
//
// MFMA operands are SWAPPED (mfma(b,a)): lane&15 = M-row, regs = 4
// consecutive N-cols -> vectorized short4/float4 epilogue stores.
// EPI=0: bias+relu^2->bf16 (short4); EPI=1: bias->f32 (float4).

template <int EPI>
__global__ __launch_bounds__(512, 2) void gemm_bt(
    const short* __restrict__ A, const short* __restrict__ B,
    const float* __restrict__ bias, void* __restrict__ Cout,
    int M, int N, int K) {
  __shared__ __align__(16) short lds[2][4][128 * 64];

  const int tid  = threadIdx.x;
  const int wave = tid >> 6;
  const int lane = tid & 63;
  const int wr = wave >> 2;          // 0..1 -> M half (128 rows)
  const int wc = wave & 3;           // 0..3 -> N quarter (64 cols)
  const int fr = lane & 15, kq = lane >> 4;

  // T1: bijective XCD swizzle (nwg % 8 == 0), column-major in-chunk
  const int nwg = gridDim.x;
  const int w = (blockIdx.x & 7) * (nwg >> 3) + (blockIdx.x >> 3);
  const int gy = M >> 8;
  const int brow = w % gy;
  const int bcol = w / gy;

  f32x4 acc[8][4];
#pragma unroll
  for (int m = 0; m < 8; ++m)
#pragma unroll
    for (int n = 0; n < 4; ++n)
      acc[m][n] = (f32x4){0.f, 0.f, 0.f, 0.f};

  const int nk = K >> 6;             // K-tiles of 64 (always even here)

  // ---- T2 swizzle (within a 128x64 slot): granule g=r*8+gc stored at
  // P = g ^ (r&7). Verified 0 bank conflicts (rounds 2-4).
  int offA[8][2], offB[4][2];
#pragma unroll
  for (int m = 0; m < 8; ++m)
#pragma unroll
    for (int kk = 0; kk < 2; ++kk) {
      int r = wr * 64 + (m & 3) * 16 + fr;     // row within slot
      int g = r * 8 + kk * 4 + kq;
      offA[m][kk] = (g ^ (r & 7)) * 16;
    }
#pragma unroll
  for (int n = 0; n < 4; ++n)
#pragma unroll
    for (int kk = 0; kk < 2; ++kk) {
      int r = wc * 32 + (n & 1) * 16 + fr;
      int g = r * 8 + kk * 4 + kq;
      offB[n][kk] = (g ^ (r & 7)) * 16;
    }

  // ---- stage source addressing (inverse swizzle on global side)
  const int i0 = tid;
  const int gl0 = i0 ^ ((i0 >> 3) & 7);
  const int r0 = gl0 >> 3, c0 = gl0 & 7;
  const size_t rstep = (size_t)128 * K;

  const short* pA[2];
  const short* pB[2];
  {
    const int rb0 = (r0 >> 5) * 64 + (r0 & 31);
#pragma unroll
    for (int h = 0; h < 2; ++h) {
      pA[h] = A + (size_t)(brow * 256 + h * 64 + r0) * K + c0 * 8;
      pB[h] = B + (size_t)(bcol * 256 + rb0 + h * 32) * K + c0 * 8;
    }
  }

  const int dst0 = wave * 512, dst1 = 4096 + wave * 512;  // shorts in slot

#define STAGE(p, buf, slot)                              \
  do {                                                   \
    short* base_ = &lds[buf][slot][0];                   \
    gload_lds16((p), base_ + dst0);                      \
    gload_lds16((p) + rstep, base_ + dst1);              \
    (p) += 64;                                           \
  } while (0)

  // ---- prologue: stage tile 0, publish, pre-read a0q,b0q(t0).
  STAGE(pA[0], 0, 0);
  STAGE(pB[0], 0, 2);
  STAGE(pA[1], 0, 1);
  STAGE(pB[1], 0, 3);
  asm volatile("s_waitcnt vmcnt(0)" ::: "memory");
  BAR();

  bf16x8 F0a[4][2], F0b[2][2], F1a[4][2], F1b[2][2];
  {
    const char* sA0 = (const char*)&lds[0][0][0];
    const char* sB0 = (const char*)&lds[0][2][0];
#pragma unroll
    for (int m = 0; m < 4; ++m)
#pragma unroll
      for (int kk = 0; kk < 2; ++kk)
        F0a[m][kk] = *(const bf16x8*)(sA0 + offA[m][kk]);
#pragma unroll
    for (int n = 0; n < 2; ++n)
#pragma unroll
      for (int kk = 0; kk < 2; ++kk)
        F0b[n][kk] = *(const bf16x8*)(sB0 + offB[n][kk]);
  }

  // body(t, a0q,b0q = this tile's pre-read frags; a0n,b0n = storage for
  // next tile's pre-read)
  auto body = [&](int t, bf16x8 (&a0q)[4][2], bf16x8 (&b0q)[2][2],
                  bf16x8 (&a0n)[4][2], bf16x8 (&b0n)[2][2]) {
    const int cur = t & 1, nxt = cur ^ 1;
    const bool s1 = (t + 1) < nk;
    const char* sA1 = (const char*)&lds[cur][1][0];
    const char* sB1 = (const char*)&lds[cur][3][0];
    const char* nA0 = (const char*)&lds[nxt][0][0];
    const char* nB0 = (const char*)&lds[nxt][2][0];

    bf16x8 a1q[4][2], b1q[2][2];

    // ---- M1: read b1q | stage A0,B0(t+1) | Q(m0-3 x n0-1)
#pragma unroll
    for (int n = 0; n < 2; ++n)
#pragma unroll
      for (int kk = 0; kk < 2; ++kk)
        b1q[n][kk] = *(const bf16x8*)(sB1 + offB[n + 2][kk]);
    if (s1) { STAGE(pA[0], nxt, 0); STAGE(pB[0], nxt, 2); }
    __builtin_amdgcn_s_setprio(1);
#pragma unroll
    for (int m = 0; m < 4; ++m)
#pragma unroll
      for (int n = 0; n < 2; ++n)
#pragma unroll
        for (int kk = 0; kk < 2; ++kk)
          acc[m][n] = __builtin_amdgcn_mfma_f32_16x16x32_bf16(
              b0q[n][kk], a0q[m][kk], acc[m][n], 0, 0, 0);
    __builtin_amdgcn_s_setprio(0);

    // ---- M2: read a1q | stage A1,B1(t+1) | Q(m0-3 x n2-3)
#pragma unroll
    for (int m = 0; m < 4; ++m)
#pragma unroll
      for (int kk = 0; kk < 2; ++kk)
        a1q[m][kk] = *(const bf16x8*)(sA1 + offA[m + 4][kk]);
    if (s1) { STAGE(pA[1], nxt, 1); STAGE(pB[1], nxt, 3); }
    __builtin_amdgcn_s_setprio(1);
#pragma unroll
    for (int m = 0; m < 4; ++m)
#pragma unroll
      for (int n = 0; n < 2; ++n)
#pragma unroll
        for (int kk = 0; kk < 2; ++kk)
          acc[m][n + 2] = __builtin_amdgcn_mfma_f32_16x16x32_bf16(
              b1q[n][kk], a0q[m][kk], acc[m][n + 2], 0, 0, 0);
    __builtin_amdgcn_s_setprio(0);

    // ---- M3: Q(m4-7 x n2-3) ; then mid publish (S1 drained)
    __builtin_amdgcn_s_setprio(1);
#pragma unroll
    for (int m = 0; m < 4; ++m)
#pragma unroll
      for (int n = 0; n < 2; ++n)
#pragma unroll
        for (int kk = 0; kk < 2; ++kk)
          acc[m + 4][n + 2] = __builtin_amdgcn_mfma_f32_16x16x32_bf16(
              b1q[n][kk], a1q[m][kk], acc[m + 4][n + 2], 0, 0, 0);
    __builtin_amdgcn_s_setprio(0);
    asm volatile("s_waitcnt vmcnt(4)" ::: "memory");
    BAR();

    // ---- M4: read a0n,b0n (t+1 head frags) | Q(m4-7 x n0-1)
    if (s1) {
#pragma unroll
      for (int m = 0; m < 4; ++m)
#pragma unroll
        for (int kk = 0; kk < 2; ++kk)
          a0n[m][kk] = *(const bf16x8*)(nA0 + offA[m][kk]);
#pragma unroll
      for (int n = 0; n < 2; ++n)
#pragma unroll
        for (int kk = 0; kk < 2; ++kk)
          b0n[n][kk] = *(const bf16x8*)(nB0 + offB[n][kk]);
    }
    __builtin_amdgcn_s_setprio(1);
#pragma unroll
    for (int m = 0; m < 4; ++m)
#pragma unroll
      for (int n = 0; n < 2; ++n)
#pragma unroll
        for (int kk = 0; kk < 2; ++kk)
          acc[m + 4][n] = __builtin_amdgcn_mfma_f32_16x16x32_bf16(
              b0q[n][kk], a1q[m][kk], acc[m + 4][n], 0, 0, 0);
    __builtin_amdgcn_s_setprio(0);

    // ---- end: publish A1,B1(t+1)
    if (s1) {
      asm volatile("s_waitcnt vmcnt(0)" ::: "memory");
      BAR();
    }
  };

  for (int t = 0; t < nk; t += 2) {
    body(t,     F0a, F0b, F1a, F1b);
    body(t + 1, F1a, F1b, F0a, F0b);
  }

  // ---- epilogue (swapped-operand layout): row = m*16 + fr,
  // cols = n*16 + q*4 + {0..3}  -> vectorized 4-wide stores.
  const int q = lane >> 4;
  if (EPI == 0) {
    short* C = (short*)Cout;
#pragma unroll
    for (int m = 0; m < 8; ++m) {
      const int row = brow * 256 + wr * 128 + m * 16 + fr;
#pragma unroll
      for (int n = 0; n < 4; ++n) {
        const int col = bcol * 256 + wc * 64 + n * 16 + q * 4;
        const float4 bv = *(const float4*)&bias[col];
        short4 o;
        float v0 = acc[m][n][0] + bv.x; v0 = v0 > 0.f ? v0 * v0 : 0.f;
        float v1 = acc[m][n][1] + bv.y; v1 = v1 > 0.f ? v1 * v1 : 0.f;
        float v2 = acc[m][n][2] + bv.z; v2 = v2 > 0.f ? v2 * v2 : 0.f;
        float v3 = acc[m][n][3] + bv.w; v3 = v3 > 0.f ? v3 * v3 : 0.f;
        o.x = f2bf(v0); o.y = f2bf(v1); o.z = f2bf(v2); o.w = f2bf(v3);
        *(short4*)&C[(size_t)row * N + col] = o;
      }
    }
  } else {
    float* C = (float*)Cout;
#pragma unroll
    for (int m = 0; m < 8; ++m) {
      const int row = brow * 256 + wr * 128 + m * 16 + fr;
#pragma unroll
      for (int n = 0; n < 4; ++n) {
        const int col = bcol * 256 + wc * 64 + n * 16 + q * 4;
        const float4 bv = *(const float4*)&bias[col];
        float4 o;
        o.x = acc[m][n][0] + bv.x;
        o.y = acc[m][n][1] + bv.y;
        o.z = acc[m][n][2] + bv.z;
        o.w = acc[m][n][3] + bv.w;
        *(float4*)&C[(size_t)row * N + col] = o;
      }
    }
  }
#undef STAGE
}

// ---- launch -------------------------------------------------------------

extern "C" void kernel_launch(void* const* d_in, const int* in_sizes, int n_in,
                              void* d_out, int out_size, void* d_ws,
                              size_t ws_size, hipStream_t stream) {
  const float* x  = (const float*)d_in[0];
  const float* w1 = (const float*)d_in[1];
  const float* b1 = (const float*)d_in[2];
  const float* w2 = (const float*)d_in[3];
  const float* b2 = (const float*)d_in[4];
  float* out = (float*)d_out;

  const int H = in_sizes[2];            // 8192
  const int D = in_sizes[4];            // 2048
  const int M = in_sizes[0] / D;        // B*S = 8192

  short* xb  = (short*)d_ws;                 // M*D
  short* w1b = xb  + (size_t)M * D;          // H*D
  short* w2b = w1b + (size_t)H * D;          // D*H
  short* act = w2b + (size_t)D * H;          // M*H

  {
    int n4 = (M * D) / 4;
    cvt_f32_bf16<<<(n4 + 255) / 256, 256, 0, stream>>>(x, xb, n4);
    n4 = (H * D) / 4;
    cvt_f32_bf16<<<(n4 + 255) / 256, 256, 0, stream>>>(w1, w1b, n4);
    n4 = (D * H) / 4;
    cvt_f32_bf16<<<(n4 + 255) / 256, 256, 0, stream>>>(w2, w2b, n4);
  }

  // GEMM1: [M,D] @ [H,D]^T -> sqrelu -> act[M,H] (bf16)
  gemm_bt<0><<<(M / 256) * (H / 256), 512, 0, stream>>>(
      xb, w1b, b1, (void*)act, M, H, D);
  // GEMM2: [M,H] @ [D,H]^T -> + b2 -> out[M,D] (f32)
  gemm_bt<1><<<(M / 256) * (D / 256), 512, 0, stream>>>(
      act, w2b, b2, (void*)out, M, D, H);
}

// Round 6
// 572.675 us; speedup vs baseline: 4.1235x; 4.1235x over previous
//
#include <hip/hip_runtime.h>
#include <hip/hip_bf16.h>
#include <stdint.h>

typedef __bf16 bf16x8 __attribute__((ext_vector_type(8)));
typedef float f32x4 __attribute__((ext_vector_type(4)));

// ---- helpers ------------------------------------------------------------

__device__ inline void gload_lds16(const void* g, void* lds) {
  __builtin_amdgcn_global_load_lds(
      (const __attribute__((address_space(1))) uint32_t*)(uintptr_t)g,
      (__attribute__((address_space(3))) uint32_t*)(uintptr_t)lds,
      16, 0, 0);
}

// Ordered LDS vector read: volatile asm keeps issue order (DS completes
// in-order) so counted lgkmcnt waits are exact.
__device__ inline bf16x8 ds_readv(uint32_t addr) {
  bf16x8 r;
  asm volatile("ds_read_b128 %0, %1" : "=v"(r) : "v"(addr));
  return r;
}

// Counted LDS wait + scheduler pin (rule #18: MFMA hoists past bare asm
// waitcnt; sched_barrier(0) right after is the fence).
#define LGKM(N) do {                                             \
    asm volatile("s_waitcnt lgkmcnt(" #N ")" ::: "memory");      \
    __builtin_amdgcn_sched_barrier(0);                           \
  } while (0)

__device__ inline short f2bf(float f) {
  union { float f; uint32_t u; } x; x.f = f;
  uint32_t u = x.u;
  u += 0x7fffu + ((u >> 16) & 1u);   // RNE
  return (short)(u >> 16);
}

#define BAR() do { asm volatile("" ::: "memory"); \
                   __builtin_amdgcn_s_barrier();  \
                   asm volatile("" ::: "memory"); } while (0)

// ---- fp32 -> bf16 convert (vectorized) ----------------------------------

__global__ __launch_bounds__(256) void cvt_f32_bf16(
    const float* __restrict__ in, short* __restrict__ out, int n4) {
  int i = blockIdx.x * 256 + threadIdx.x;
  if (i < n4) {
    float4 v = reinterpret_cast<const float4*>(in)[i];
    short4 o;
    o.x = f2bf(v.x); o.y = f2bf(v.y); o.z = f2bf(v.z); o.w = f2bf(v.w);
    reinterpret_cast<short4*>(out)[i] = o;
  }
}

// ---- GEMM: C[M,N] = A[M,K] @ B[N,K]^T, bf16 in, fp32 acc ---------------
// Round-4 self-contained tile structure (1 barrier/tile, no cross-tile reg
// state -> no spill) + hand-pipelined LDS reads:
//   issue 24 ordered asm ds_read_b128 {bq0(4), a0q(8), a1q(8), bq1(4)}
//   LGKM(12) -> M1(m0-3,n0-1)   [a1q,bq1 drain under M1]
//   LGKM(4)  -> M2(m4-7,n0-1)   [bq1 drains under M2]
//   LGKM(0)  -> M3(m4-7,n2-3), M4(m0-3,n2-3)
// Stages for t+1 issued at region start; single vmcnt(0)+barrier at tile
// end (stage had ~full tile in flight >= HBM latency -> drain ~free).
//
// 256x256 tile, BK=64, 8 waves (2Mx4N), per-wave 128x64 = acc[8][4].
// LDS: 2 buf x 4 slots x [128x64] bf16 = 128 KiB; slot0 A0(m0-3),
// slot1 A1(m4-7), slot2 B0(n0-1), slot3 B1(n2-3).
// MFMA operands SWAPPED (mfma(b,a), verified r5): lane&15 = M-row, 4 acc
// regs = 4 consecutive N-cols -> vectorized epilogue stores.
// EPI=0: bias+relu^2->bf16 (short4); EPI=1: bias->f32 (float4).

template <int EPI>
__global__ __launch_bounds__(512, 2) void gemm_bt(
    const short* __restrict__ A, const short* __restrict__ B,
    const float* __restrict__ bias, void* __restrict__ Cout,
    int M, int N, int K) {
  __shared__ __align__(16) short lds[2][4][128 * 64];

  const int tid  = threadIdx.x;
  const int wave = tid >> 6;
  const int lane = tid & 63;
  const int wr = wave >> 2;          // 0..1 -> M half (128 rows)
  const int wc = wave & 3;           // 0..3 -> N quarter (64 cols)
  const int fr = lane & 15, kq = lane >> 4;

  // T1: bijective XCD swizzle (nwg % 8 == 0), column-major in-chunk
  const int nwg = gridDim.x;
  const int w = (blockIdx.x & 7) * (nwg >> 3) + (blockIdx.x >> 3);
  const int gy = M >> 8;
  const int brow = w % gy;
  const int bcol = w / gy;

  f32x4 acc[8][4];
#pragma unroll
  for (int m = 0; m < 8; ++m)
#pragma unroll
    for (int n = 0; n < 4; ++n)
      acc[m][n] = (f32x4){0.f, 0.f, 0.f, 0.f};

  const int nk = K >> 6;             // K-tiles of 64

  // ---- T2 swizzle (within a 128x64 slot): granule g=r*8+gc stored at
  // P = g ^ (r&7). Verified 0 bank conflicts (rounds 2-5).
  // Precompute absolute LDS byte addresses for buffer 0; buffer 1 = +64KiB.
  const uint32_t LB = (uint32_t)(uintptr_t)&lds[0][0][0];
  uint32_t aA[4][2], aB[2][2];
#pragma unroll
  for (int m = 0; m < 4; ++m)
#pragma unroll
    for (int kk = 0; kk < 2; ++kk) {
      int r = wr * 64 + m * 16 + fr;
      int g = r * 8 + kk * 4 + kq;
      aA[m][kk] = LB + (uint32_t)((g ^ (r & 7)) * 16);
    }
#pragma unroll
  for (int n = 0; n < 2; ++n)
#pragma unroll
    for (int kk = 0; kk < 2; ++kk) {
      int r = wc * 32 + n * 16 + fr;
      int g = r * 8 + kk * 4 + kq;
      aB[n][kk] = LB + (uint32_t)((g ^ (r & 7)) * 16);
    }

  // ---- stage source addressing (inverse swizzle on global side)
  const int i0 = tid;
  const int gl0 = i0 ^ ((i0 >> 3) & 7);
  const int r0 = gl0 >> 3, c0 = gl0 & 7;
  const size_t rstep = (size_t)128 * K;

  const short* pA[2];
  const short* pB[2];
  {
    const int rb0 = (r0 >> 5) * 64 + (r0 & 31);
#pragma unroll
    for (int h = 0; h < 2; ++h) {
      pA[h] = A + (size_t)(brow * 256 + h * 64 + r0) * K + c0 * 8;
      pB[h] = B + (size_t)(bcol * 256 + rb0 + h * 32) * K + c0 * 8;
    }
  }

  const int dst0 = wave * 512, dst1 = 4096 + wave * 512;  // shorts in slot

#define STAGE(p, buf, slot)                              \
  do {                                                   \
    short* base_ = &lds[buf][slot][0];                   \
    gload_lds16((p), base_ + dst0);                      \
    gload_lds16((p) + rstep, base_ + dst1);              \
    (p) += 64;                                           \
  } while (0)

  // ---- prologue: stage tile 0, publish.
  STAGE(pA[0], 0, 0);
  STAGE(pA[1], 0, 1);
  STAGE(pB[0], 0, 2);
  STAGE(pB[1], 0, 3);
  asm volatile("s_waitcnt vmcnt(0)" ::: "memory");
  BAR();

  for (int t = 0; t < nk; ++t) {
    const int cur = t & 1, nxt = cur ^ 1;
    const bool s1 = (t + 1) < nk;

    // stage all of tile t+1 (lands under this tile's MFMA; vmcnt only)
    if (s1) {
      STAGE(pA[0], nxt, 0);
      STAGE(pA[1], nxt, 1);
      STAGE(pB[0], nxt, 2);
      STAGE(pB[1], nxt, 3);
    }

    const uint32_t cb = (uint32_t)cur << 16;   // buffer byte offset

    bf16x8 bq0[2][2], a0q[4][2], a1q[4][2], bq1[2][2];
    // issue order (lgkm-counted): bq0(4), a0q(8), a1q(8), bq1(4)
#pragma unroll
    for (int n = 0; n < 2; ++n)
#pragma unroll
      for (int kk = 0; kk < 2; ++kk)
        bq0[n][kk] = ds_readv(aB[n][kk] + cb + 32768u);      // slot2 B0
#pragma unroll
    for (int m = 0; m < 4; ++m)
#pragma unroll
      for (int kk = 0; kk < 2; ++kk)
        a0q[m][kk] = ds_readv(aA[m][kk] + cb);               // slot0 A0
#pragma unroll
    for (int m = 0; m < 4; ++m)
#pragma unroll
      for (int kk = 0; kk < 2; ++kk)
        a1q[m][kk] = ds_readv(aA[m][kk] + cb + 16384u);      // slot1 A1
#pragma unroll
    for (int n = 0; n < 2; ++n)
#pragma unroll
      for (int kk = 0; kk < 2; ++kk)
        bq1[n][kk] = ds_readv(aB[n][kk] + cb + 49152u);      // slot3 B1

    // M1: needs bq0+a0q (first 12 reads) -> 12 may remain outstanding
    LGKM(12);
    __builtin_amdgcn_s_setprio(1);
#pragma unroll
    for (int m = 0; m < 4; ++m)
#pragma unroll
      for (int n = 0; n < 2; ++n)
#pragma unroll
        for (int kk = 0; kk < 2; ++kk)
          acc[m][n] = __builtin_amdgcn_mfma_f32_16x16x32_bf16(
              bq0[n][kk], a0q[m][kk], acc[m][n], 0, 0, 0);
    __builtin_amdgcn_s_setprio(0);

    // M2: needs a1q (reads 13-20) -> 4 may remain outstanding
    LGKM(4);
    __builtin_amdgcn_s_setprio(1);
#pragma unroll
    for (int m = 0; m < 4; ++m)
#pragma unroll
      for (int n = 0; n < 2; ++n)
#pragma unroll
        for (int kk = 0; kk < 2; ++kk)
          acc[m + 4][n] = __builtin_amdgcn_mfma_f32_16x16x32_bf16(
              bq0[n][kk], a1q[m][kk], acc[m + 4][n], 0, 0, 0);
    __builtin_amdgcn_s_setprio(0);

    // M3 + M4: need bq1
    LGKM(0);
    __builtin_amdgcn_s_setprio(1);
#pragma unroll
    for (int m = 0; m < 4; ++m)
#pragma unroll
      for (int n = 0; n < 2; ++n)
#pragma unroll
        for (int kk = 0; kk < 2; ++kk)
          acc[m + 4][n + 2] = __builtin_amdgcn_mfma_f32_16x16x32_bf16(
              bq1[n][kk], a1q[m][kk], acc[m + 4][n + 2], 0, 0, 0);
    __builtin_amdgcn_s_setprio(0);
    __builtin_amdgcn_s_setprio(1);
#pragma unroll
    for (int m = 0; m < 4; ++m)
#pragma unroll
      for (int n = 0; n < 2; ++n)
#pragma unroll
        for (int kk = 0; kk < 2; ++kk)
          acc[m][n + 2] = __builtin_amdgcn_mfma_f32_16x16x32_bf16(
              bq1[n][kk], a0q[m][kk], acc[m][n + 2], 0, 0, 0);
    __builtin_amdgcn_s_setprio(0);

    // tile boundary: publish t+1
    if (s1) {
      asm volatile("s_waitcnt vmcnt(0)" ::: "memory");
      BAR();
    }
  }

  // ---- epilogue (swapped-operand layout, verified r5): row = m*16+fr,
  // cols = n*16 + q*4 + {0..3} -> 4-wide stores.
  const int q = lane >> 4;
  if (EPI == 0) {
    short* C = (short*)Cout;
#pragma unroll
    for (int m = 0; m < 8; ++m) {
      const int row = brow * 256 + wr * 128 + m * 16 + fr;
#pragma unroll
      for (int n = 0; n < 4; ++n) {
        const int col = bcol * 256 + wc * 64 + n * 16 + q * 4;
        const float4 bv = *(const float4*)&bias[col];
        short4 o;
        float v0 = acc[m][n][0] + bv.x; v0 = v0 > 0.f ? v0 * v0 : 0.f;
        float v1 = acc[m][n][1] + bv.y; v1 = v1 > 0.f ? v1 * v1 : 0.f;
        float v2 = acc[m][n][2] + bv.z; v2 = v2 > 0.f ? v2 * v2 : 0.f;
        float v3 = acc[m][n][3] + bv.w; v3 = v3 > 0.f ? v3 * v3 : 0.f;
        o.x = f2bf(v0); o.y = f2bf(v1); o.z = f2bf(v2); o.w = f2bf(v3);
        *(short4*)&C[(size_t)row * N + col] = o;
      }
    }
  } else {
    float* C = (float*)Cout;
#pragma unroll
    for (int m = 0; m < 8; ++m) {
      const int row = brow * 256 + wr * 128 + m * 16 + fr;
#pragma unroll
      for (int n = 0; n < 4; ++n) {
        const int col = bcol * 256 + wc * 64 + n * 16 + q * 4;
        const float4 bv = *(const float4*)&bias[col];
        float4 o;
        o.x = acc[m][n][0] + bv.x;
        o.y = acc[m][n][1] + bv.y;
        o.z = acc[m][n][2] + bv.z;
        o.w = acc[m][n][3] + bv.w;
        *(float4*)&C[(size_t)row * N + col] = o;
      }
    }
  }
#undef STAGE
}

// ---- launch -------------------------------------------------------------

extern "C" void kernel_launch(void* const* d_in, const int* in_sizes, int n_in,
                              void* d_out, int out_size, void* d_ws,
                              size_t ws_size, hipStream_t stream) {
  const float* x  = (const float*)d_in[0];
  const float* w1 = (const float*)d_in[1];
  const float* b1 = (const float*)d_in[2];
  const float* w2 = (const float*)d_in[3];
  const float* b2 = (const float*)d_in[4];
  float* out = (float*)d_out;

  const int H = in_sizes[2];            // 8192
  const int D = in_sizes[4];            // 2048
  const int M = in_sizes[0] / D;        // B*S = 8192

  short* xb  = (short*)d_ws;                 // M*D
  short* w1b = xb  + (size_t)M * D;          // H*D
  short* w2b = w1b + (size_t)H * D;          // D*H
  short* act = w2b + (size_t)D * H;          // M*H

  {
    int n4 = (M * D) / 4;
    cvt_f32_bf16<<<(n4 + 255) / 256, 256, 0, stream>>>(x, xb, n4);
    n4 = (H * D) / 4;
    cvt_f32_bf16<<<(n4 + 255) / 256, 256, 0, stream>>>(w1, w1b, n4);
    n4 = (D * H) / 4;
    cvt_f32_bf16<<<(n4 + 255) / 256, 256, 0, stream>>>(w2, w2b, n4);
  }

  // GEMM1: [M,D] @ [H,D]^T -> sqrelu -> act[M,H] (bf16)
  gemm_bt<0><<<(M / 256) * (H / 256), 512, 0, stream>>>(
      xb, w1b, b1, (void*)act, M, H, D);
  // GEMM2: [M,H] @ [D,H]^T -> + b2 -> out[M,D] (f32)
  gemm_bt<1><<<(M / 256) * (D / 256), 512, 0, stream>>>(
      act, w2b, b2, (void*)out, M, D, H);
}

// Round 8
// 544.946 us; speedup vs baseline: 4.3333x; 1.0509x over previous
//
#include <hip/hip_runtime.h>
#include <hip/hip_bf16.h>
#include <stdint.h>

typedef __bf16 bf16x8 __attribute__((ext_vector_type(8)));
typedef float f32x4 __attribute__((ext_vector_type(4)));

// ---- helpers ------------------------------------------------------------

__device__ inline void gload_lds16(const void* g, void* lds) {
  __builtin_amdgcn_global_load_lds(
      (const __attribute__((address_space(1))) uint32_t*)(uintptr_t)g,
      (__attribute__((address_space(3))) uint32_t*)(uintptr_t)lds,
      16, 0, 0);
}

// Ordered LDS vector read (volatile asm: issue order preserved; DS
// completion in-order per wave -> counted lgkmcnt is exact).
__device__ inline bf16x8 ds_readv(uint32_t addr) {
  bf16x8 r;
  asm volatile("ds_read_b128 %0, %1" : "=v"(r) : "v"(addr));
  return r;
}

#define LGKM(N) do {                                             \
    asm volatile("s_waitcnt lgkmcnt(" #N ")" ::: "memory");      \
    __builtin_amdgcn_sched_barrier(0);                           \
  } while (0)
#define VM(N) do {                                               \
    asm volatile("s_waitcnt vmcnt(" #N ")" ::: "memory");        \
    __builtin_amdgcn_sched_barrier(0);                           \
  } while (0)

__device__ inline short f2bf(float f) {
  union { float f; uint32_t u; } x; x.f = f;
  uint32_t u = x.u;
  u += 0x7fffu + ((u >> 16) & 1u);   // RNE
  return (short)(u >> 16);
}

#define BAR() do { asm volatile("" ::: "memory"); \
                   __builtin_amdgcn_s_barrier();  \
                   asm volatile("" ::: "memory"); } while (0)

// ---- fp32 -> bf16 convert (vectorized) ----------------------------------

__global__ __launch_bounds__(256) void cvt_f32_bf16(
    const float* __restrict__ in, short* __restrict__ out, int n4) {
  int i = blockIdx.x * 256 + threadIdx.x;
  if (i < n4) {
    float4 v = reinterpret_cast<const float4*>(in)[i];
    short4 o;
    o.x = f2bf(v.x); o.y = f2bf(v.y); o.z = f2bf(v.z); o.w = f2bf(v.w);
    reinterpret_cast<short4*>(out)[i] = o;
  }
}

// ---- GEMM: C[M,N] = A[M,K] @ B[N,K]^T, bf16 in, fp32 acc ---------------
// m201 8-phase port, CORRECTED vmcnt discipline (r7 bug): counted VM(10)
// sits immediately BEFORE each phase's closing s_barrier (vmcnt is
// per-wave; the barrier is what publishes "all waves' stages landed" to
// the readers on the other side). Reads still cross the MID barrier and
// are waited with LGKM(0) after it (the overlap lever).
//
// Per phase: {reads | 1 stage | [lgkm(8) if 12 reads]} -> BAR(mid) ->
//            LGKM(0) -> setprio(1) 16xMFMA setprio(0) -> VM(10) -> BAR.
//
// 256x256 tile, BK=64, 8 waves (2Mx4N), per-wave 128x64 = acc[8][4].
// LDS: 2 buf x 4 slots x [128x64] bf16 = 128 KiB; byte offsets:
// A0=+0, A1=+16384, B0=+32768, B1=+49152; buf1=+65536.
//
// Iter i = K-tiles 2i (buf0) / 2i+1 (buf1), 4 phases each.
// Reads: Ph1/5 a0q+bq0 (12), Ph2/6 bq1 (4), Ph3/7 a1q (8), Ph4/8 none.
// Stage stream: Ph1 A1(2i+1), Ph2 A0(2i+2), Ph3 B0(2i+2), Ph4 B1(2i+2),
//               Ph5 A1(2i+2), Ph6 A0(2i+3), Ph7 B0(2i+3), Ph8 B1(2i+3).
// Readiness ledger: each phase's read-halftile was staged 5 phases
// earlier with exactly 5 stages (10 gloads) issued after it -> VM(10)
// before the closing BAR of the PRECEDING phase guarantees it. Uniform.
// Clobber ledger: every slot's restage is issued >=1 closing barrier
// after that slot's reads completed (reads complete at LGKM(0), before
// the same phase's closing BAR; restage is in a later phase).  All safe.
// Tail: last iteration peeled — only stage is Ph1's A1(nk-1); VM(10)
// would under-constrain with stages skipped, so one VM(0) at Ph1-close
// drains everything; remaining tail phases need no VM.
// MFMA operands SWAPPED (mfma(b,a), verified r5/r6): lane&15 = M-row,
// 4 acc regs = 4 consecutive N-cols -> vectorized epilogue stores.
// EPI=0: bias+relu^2->bf16 (short4); EPI=1: bias->f32 (float4).

template <int EPI>
__global__ __launch_bounds__(512, 2) void gemm_bt(
    const short* __restrict__ A, const short* __restrict__ B,
    const float* __restrict__ bias, void* __restrict__ Cout,
    int M, int N, int K) {
  __shared__ __align__(16) short lds[2][4][128 * 64];

  const int tid  = threadIdx.x;
  const int wave = tid >> 6;
  const int lane = tid & 63;
  const int wr = wave >> 2;          // 0..1 -> M half (128 rows)
  const int wc = wave & 3;           // 0..3 -> N quarter (64 cols)
  const int fr = lane & 15, kq = lane >> 4;

  // T1: bijective XCD swizzle (nwg % 8 == 0), column-major in-chunk
  const int nwg = gridDim.x;
  const int w = (blockIdx.x & 7) * (nwg >> 3) + (blockIdx.x >> 3);
  const int gy = M >> 8;
  const int brow = w % gy;
  const int bcol = w / gy;

  f32x4 acc[8][4];
#pragma unroll
  for (int m = 0; m < 8; ++m)
#pragma unroll
    for (int n = 0; n < 4; ++n)
      acc[m][n] = (f32x4){0.f, 0.f, 0.f, 0.f};

  const int nk = K >> 6;             // K-tiles of 64 (even; nk>=4 here)

  // ---- T2 swizzle (within a 128x64 slot): granule g=r*8+gc stored at
  // P = g ^ (r&7). Verified 0 bank conflicts (rounds 2-6).
  const uint32_t LB = (uint32_t)(uintptr_t)&lds[0][0][0];
  uint32_t aA[4][2], aB[2][2];
#pragma unroll
  for (int m = 0; m < 4; ++m)
#pragma unroll
    for (int kk = 0; kk < 2; ++kk) {
      int r = wr * 64 + m * 16 + fr;
      int g = r * 8 + kk * 4 + kq;
      aA[m][kk] = LB + (uint32_t)((g ^ (r & 7)) * 16);
    }
#pragma unroll
  for (int n = 0; n < 2; ++n)
#pragma unroll
    for (int kk = 0; kk < 2; ++kk) {
      int r = wc * 32 + n * 16 + fr;
      int g = r * 8 + kk * 4 + kq;
      aB[n][kk] = LB + (uint32_t)((g ^ (r & 7)) * 16);
    }

  // ---- stage source addressing (inverse swizzle on global side)
  const int i0 = tid;
  const int gl0 = i0 ^ ((i0 >> 3) & 7);
  const int r0 = gl0 >> 3, c0 = gl0 & 7;
  const size_t rstep = (size_t)128 * K;

  const short* pA[2];
  const short* pB[2];
  {
    const int rb0 = (r0 >> 5) * 64 + (r0 & 31);
#pragma unroll
    for (int h = 0; h < 2; ++h) {
      pA[h] = A + (size_t)(brow * 256 + h * 64 + r0) * K + c0 * 8;
      pB[h] = B + (size_t)(bcol * 256 + rb0 + h * 32) * K + c0 * 8;
    }
  }

  const int dst0 = wave * 512, dst1 = 4096 + wave * 512;  // shorts in slot

#define STAGE(p, buf, slot)                              \
  do {                                                   \
    short* base_ = &lds[buf][slot][0];                   \
    gload_lds16((p), base_ + dst0);                      \
    gload_lds16((p) + rstep, base_ + dst1);              \
    (p) += 64;                                           \
  } while (0)

  // fragment regs + quadrant clusters (swapped operands)
  bf16x8 a0q[4][2], a1q[4][2], bq0[2][2], bq1[2][2];
  auto Q1 = [&]() {
#pragma unroll
    for (int m = 0; m < 4; ++m)
#pragma unroll
      for (int n = 0; n < 2; ++n)
#pragma unroll
        for (int kk = 0; kk < 2; ++kk)
          acc[m][n] = __builtin_amdgcn_mfma_f32_16x16x32_bf16(
              bq0[n][kk], a0q[m][kk], acc[m][n], 0, 0, 0);
  };
  auto Q2 = [&]() {
#pragma unroll
    for (int m = 0; m < 4; ++m)
#pragma unroll
      for (int n = 0; n < 2; ++n)
#pragma unroll
        for (int kk = 0; kk < 2; ++kk)
          acc[m][n + 2] = __builtin_amdgcn_mfma_f32_16x16x32_bf16(
              bq1[n][kk], a0q[m][kk], acc[m][n + 2], 0, 0, 0);
  };
  auto Q3 = [&]() {
#pragma unroll
    for (int m = 0; m < 4; ++m)
#pragma unroll
      for (int n = 0; n < 2; ++n)
#pragma unroll
        for (int kk = 0; kk < 2; ++kk)
          acc[m + 4][n + 2] = __builtin_amdgcn_mfma_f32_16x16x32_bf16(
              bq1[n][kk], a1q[m][kk], acc[m + 4][n + 2], 0, 0, 0);
  };
  auto Q4 = [&]() {
#pragma unroll
    for (int m = 0; m < 4; ++m)
#pragma unroll
      for (int n = 0; n < 2; ++n)
#pragma unroll
        for (int kk = 0; kk < 2; ++kk)
          acc[m + 4][n] = __builtin_amdgcn_mfma_f32_16x16x32_bf16(
              bq0[n][kk], a1q[m][kk], acc[m + 4][n], 0, 0, 0);
  };
  auto RD_A0 = [&](uint32_t cb) {
#pragma unroll
    for (int m = 0; m < 4; ++m)
#pragma unroll
      for (int kk = 0; kk < 2; ++kk)
        a0q[m][kk] = ds_readv(aA[m][kk] + cb);
  };
  auto RD_A1 = [&](uint32_t cb) {
#pragma unroll
    for (int m = 0; m < 4; ++m)
#pragma unroll
      for (int kk = 0; kk < 2; ++kk)
        a1q[m][kk] = ds_readv(aA[m][kk] + cb + 16384u);
  };
  auto RD_B0 = [&](uint32_t cb) {
#pragma unroll
    for (int n = 0; n < 2; ++n)
#pragma unroll
      for (int kk = 0; kk < 2; ++kk)
        bq0[n][kk] = ds_readv(aB[n][kk] + cb + 32768u);
  };
  auto RD_B1 = [&](uint32_t cb) {
#pragma unroll
    for (int n = 0; n < 2; ++n)
#pragma unroll
      for (int kk = 0; kk < 2; ++kk)
        bq1[n][kk] = ds_readv(aB[n][kk] + cb + 49152u);
  };

#define PRIO_ON  __builtin_amdgcn_s_setprio(1)
#define PRIO_OFF __builtin_amdgcn_s_setprio(0)

  // ---- prologue: tile0 full + tile1 {A0,B0,B1}; VM BEFORE BAR (publish).
  STAGE(pA[0], 0, 0);   // A0(0)
  STAGE(pB[0], 0, 2);   // B0(0)
  STAGE(pB[1], 0, 3);   // B1(0)
  STAGE(pA[1], 0, 1);   // A1(0)
  STAGE(pA[0], 1, 0);   // A0(1)
  STAGE(pB[0], 1, 2);   // B0(1)
  STAGE(pB[1], 1, 3);   // B1(1)
  VM(6);                // tile 0 (oldest 8) landed
  BAR();

  const int niter = nk >> 1;
  for (int i = 0; i < niter - 1; ++i) {
    // ============ K-tile 2i (buf0, cb=0) ============
    // Ph1
    RD_A0(0); RD_B0(0);
    STAGE(pA[1], 1, 1);                 // A1(2i+1)
    LGKM(8);
    BAR();
    LGKM(0);
    PRIO_ON; Q1(); PRIO_OFF;
    VM(10); BAR();
    // Ph2
    RD_B1(0);
    STAGE(pA[0], 0, 0);                 // A0(2i+2)
    BAR();
    LGKM(0);
    PRIO_ON; Q2(); PRIO_OFF;
    VM(10); BAR();
    // Ph3
    RD_A1(0);
    STAGE(pB[0], 0, 2);                 // B0(2i+2)
    BAR();
    LGKM(0);
    PRIO_ON; Q3(); PRIO_OFF;
    VM(10); BAR();
    // Ph4
    STAGE(pB[1], 0, 3);                 // B1(2i+2)
    BAR();
    PRIO_ON; Q4(); PRIO_OFF;
    VM(10); BAR();

    // ============ K-tile 2i+1 (buf1, cb=65536) ============
    // Ph5
    RD_A0(65536u); RD_B0(65536u);
    STAGE(pA[1], 0, 1);                 // A1(2i+2)
    LGKM(8);
    BAR();
    LGKM(0);
    PRIO_ON; Q1(); PRIO_OFF;
    VM(10); BAR();
    // Ph6
    RD_B1(65536u);
    STAGE(pA[0], 1, 0);                 // A0(2i+3)
    BAR();
    LGKM(0);
    PRIO_ON; Q2(); PRIO_OFF;
    VM(10); BAR();
    // Ph7
    RD_A1(65536u);
    STAGE(pB[0], 1, 2);                 // B0(2i+3)
    BAR();
    LGKM(0);
    PRIO_ON; Q3(); PRIO_OFF;
    VM(10); BAR();
    // Ph8
    STAGE(pB[1], 1, 3);                 // B1(2i+3)
    BAR();
    PRIO_ON; Q4(); PRIO_OFF;
    VM(10); BAR();
  }

  // ---- tail iteration (tiles nk-2 / nk-1): only stage = Ph1's A1(nk-1);
  // one VM(0) publish at Ph1-close, then drain-free phases.
  // Ph1
  RD_A0(0); RD_B0(0);
  STAGE(pA[1], 1, 1);                   // A1(nk-1)
  LGKM(8);
  BAR();
  LGKM(0);
  PRIO_ON; Q1(); PRIO_OFF;
  VM(0); BAR();                          // everything landed
  // Ph2
  RD_B1(0); BAR(); LGKM(0);
  PRIO_ON; Q2(); PRIO_OFF; BAR();
  // Ph3
  RD_A1(0); BAR(); LGKM(0);
  PRIO_ON; Q3(); PRIO_OFF; BAR();
  // Ph4
  PRIO_ON; Q4(); PRIO_OFF;
  BAR();
  // Ph5
  RD_A0(65536u); RD_B0(65536u); BAR(); LGKM(0);
  PRIO_ON; Q1(); PRIO_OFF; BAR();
  // Ph6
  RD_B1(65536u); BAR(); LGKM(0);
  PRIO_ON; Q2(); PRIO_OFF; BAR();
  // Ph7
  RD_A1(65536u); BAR(); LGKM(0);
  PRIO_ON; Q3(); PRIO_OFF; BAR();
  // Ph8
  PRIO_ON; Q4(); PRIO_OFF;

  // ---- epilogue (swapped-operand layout, verified r5/r6): row=m*16+fr,
  // cols = n*16 + q*4 + {0..3} -> 4-wide stores.
  const int q = lane >> 4;
  if (EPI == 0) {
    short* C = (short*)Cout;
#pragma unroll
    for (int m = 0; m < 8; ++m) {
      const int row = brow * 256 + wr * 128 + m * 16 + fr;
#pragma unroll
      for (int n = 0; n < 4; ++n) {
        const int col = bcol * 256 + wc * 64 + n * 16 + q * 4;
        const float4 bv = *(const float4*)&bias[col];
        short4 o;
        float v0 = acc[m][n][0] + bv.x; v0 = v0 > 0.f ? v0 * v0 : 0.f;
        float v1 = acc[m][n][1] + bv.y; v1 = v1 > 0.f ? v1 * v1 : 0.f;
        float v2 = acc[m][n][2] + bv.z; v2 = v2 > 0.f ? v2 * v2 : 0.f;
        float v3 = acc[m][n][3] + bv.w; v3 = v3 > 0.f ? v3 * v3 : 0.f;
        o.x = f2bf(v0); o.y = f2bf(v1); o.z = f2bf(v2); o.w = f2bf(v3);
        *(short4*)&C[(size_t)row * N + col] = o;
      }
    }
  } else {
    float* C = (float*)Cout;
#pragma unroll
    for (int m = 0; m < 8; ++m) {
      const int row = brow * 256 + wr * 128 + m * 16 + fr;
#pragma unroll
      for (int n = 0; n < 4; ++n) {
        const int col = bcol * 256 + wc * 64 + n * 16 + q * 4;
        const float4 bv = *(const float4*)&bias[col];
        float4 o;
        o.x = acc[m][n][0] + bv.x;
        o.y = acc[m][n][1] + bv.y;
        o.z = acc[m][n][2] + bv.z;
        o.w = acc[m][n][3] + bv.w;
        *(float4*)&C[(size_t)row * N + col] = o;
      }
    }
  }
#undef STAGE
}

// ---- launch -------------------------------------------------------------

extern "C" void kernel_launch(void* const* d_in, const int* in_sizes, int n_in,
                              void* d_out, int out_size, void* d_ws,
                              size_t ws_size, hipStream_t stream) {
  const float* x  = (const float*)d_in[0];
  const float* w1 = (const float*)d_in[1];
  const float* b1 = (const float*)d_in[2];
  const float* w2 = (const float*)d_in[3];
  const float* b2 = (const float*)d_in[4];
  float* out = (float*)d_out;

  const int H = in_sizes[2];            // 8192
  const int D = in_sizes[4];            // 2048
  const int M = in_sizes[0] / D;        // B*S = 8192

  short* xb  = (short*)d_ws;                 // M*D
  short* w1b = xb  + (size_t)M * D;          // H*D
  short* w2b = w1b + (size_t)H * D;          // D*H
  short* act = w2b + (size_t)D * H;          // M*H

  {
    int n4 = (M * D) / 4;
    cvt_f32_bf16<<<(n4 + 255) / 256, 256, 0, stream>>>(x, xb, n4);
    n4 = (H * D) / 4;
    cvt_f32_bf16<<<(n4 + 255) / 256, 256, 0, stream>>>(w1, w1b, n4);
    n4 = (D * H) / 4;
    cvt_f32_bf16<<<(n4 + 255) / 256, 256, 0, stream>>>(w2, w2b, n4);
  }

  // GEMM1: [M,D] @ [H,D]^T -> sqrelu -> act[M,H] (bf16)
  gemm_bt<0><<<(M / 256) * (H / 256), 512, 0, stream>>>(
      xb, w1b, b1, (void*)act, M, H, D);
  // GEMM2: [M,H] @ [D,H]^T -> + b2 -> out[M,D] (f32)
  gemm_bt<1><<<(M / 256) * (D / 256), 512, 0, stream>>>(
      act, w2b, b2, (void*)out, M, D, H);
}